// Round 10
// baseline (30.503 us; speedup 1.0000x reference)
//
#include <hip/hip_runtime.h>
#include <math.h>

// Problem constants (B=8, N=M=4096, D=2).
// d2[n][m] = ||x_n - t_m||^2 = dot(A_n, B_m) with
//   A_n = [-2xn, -2yn, |x_n|^2, 1],  B_m = [tx, ty, 1, |t_m|^2]  (K=4)
// computed EXACTLY (to ~1e-5) in one mfma_f32_16x16x32_bf16 via 3-way bf16
// splits arranged as 6 product-pair groups over K=24 (pairs: hh,hm,hl,mh,mm,lh).
#define NPTS 4096

typedef short bf16x8 __attribute__((ext_vector_type(8)));
typedef float f32x4  __attribute__((ext_vector_type(4)));
#define INF __builtin_huge_valf()

static __device__ __forceinline__ unsigned short rne16(float v, float* f) {
    unsigned u = __float_as_uint(v);
    unsigned r = (u + 0x7FFFu + ((u >> 16) & 1u)) & 0xFFFF0000u;
    *f = __uint_as_float(r);
    return (unsigned short)(r >> 16);
}
struct S3 { unsigned short h, m, l; };
static __device__ __forceinline__ S3 split3(float v) {
    S3 s; float hf, mf, lf;
    s.h = rne16(v, &hf);
    float r1 = v - hf;
    s.m = rne16(r1, &mf);
    float r2 = r1 - mf;
    s.l = rne16(r2, &lf);
    return s;
}

// 256 blocks = 8 batches x 8 n-chunks(512) x 4 m-quarters(1024); 512 thr.
// Wave w: 4 A-tiles (64 n) kept in regs; loop 64 B-tiles from LDS, 2/iter.
// nmin (d_x_to_t) in regs -> shfl-reduce -> global atomicMin(int).
// mmin (d_t_to_x) per-rowgroup LDS atomicMin -> fold -> global atomicMin.
__global__ __launch_bounds__(512, 2) void chamfer_gemm(
    const float* __restrict__ x, const float* __restrict__ tgt,
    int* __restrict__ gn, int* __restrict__ gm)
{
    __shared__ short bfrag[64][64][8];   // 64 KB B fragments (frag-layout)
    __shared__ int   smmin[4096];        // 16 KB col-min partials [rowgrp][1024]

    const int bid = blockIdx.x;
    const int b   = bid >> 5;
    const int nc  = (bid >> 2) & 7;
    const int mq  = bid & 3;
    const int t   = threadIdx.x;
    const int l   = t & 63, w = t >> 6;
    const int kw  = l >> 4, row = l & 15;

    #pragma unroll
    for (int k = 0; k < 8; ++k) smmin[t + 512 * k] = 0x7F7F7F7F;

    // ---- build B fragments: 2 points/thread, 4 K-windows each ----
    // B groups over K: [hi, mid, lo, hi, mid, hi] (pairs with A's hh,hm,hl,mh,mm,lh)
    const float2* bp = (const float2*)(tgt + b * (NPTS * 2)) + mq * 1024;
    #pragma unroll
    for (int k = 0; k < 2; ++k) {
        const int ml = t + k * 512;
        const float2 p = bp[ml];
        const S3 sx = split3(p.x), sy = split3(p.y);
        const S3 sq = split3(fmaf(p.x, p.x, p.y * p.y));
        const unsigned H0 = (unsigned)sx.h | ((unsigned)sy.h << 16);
        const unsigned H1 = 0x3F80u      | ((unsigned)sq.h << 16);
        const unsigned M0 = (unsigned)sx.m | ((unsigned)sy.m << 16);
        const unsigned M1 =                 ((unsigned)sq.m << 16);
        const unsigned L0 = (unsigned)sx.l | ((unsigned)sy.l << 16);
        const unsigned L1 =                 ((unsigned)sq.l << 16);
        const int tile = ml >> 4, col = ml & 15;
        *(uint4*)&bfrag[tile][ 0 + col][0] = make_uint4(H0, H1, M0, M1); // k0-7  [H|M]
        *(uint4*)&bfrag[tile][16 + col][0] = make_uint4(L0, L1, H0, H1); // k8-15 [L|H]
        *(uint4*)&bfrag[tile][32 + col][0] = make_uint4(M0, M1, H0, H1); // k16-23[M|H]
        *(uint4*)&bfrag[tile][48 + col][0] = make_uint4(0, 0, 0, 0);     // k24-31 0
    }

    // ---- build A fragments in registers: 4 tiles of 16 rows ----
    // A groups over K: [hi, hi, hi, mid, mid, lo]
    const float2* ap = (const float2*)(x + b * (NPTS * 2));
    bf16x8 af[4];
    #pragma unroll
    for (int tt = 0; tt < 4; ++tt) {
        const float2 p = ap[nc * 512 + w * 64 + tt * 16 + row];
        const S3 sx = split3(-2.f * p.x), sy = split3(-2.f * p.y);
        const S3 sq = split3(fmaf(p.x, p.x, p.y * p.y));
        // lo-half quad (k 0-3 of window): kw0,1 -> H ; kw2 -> M ; kw3 -> 0
        const unsigned short e0 = kw < 2 ? sx.h : (kw == 2 ? sx.m : (unsigned short)0);
        const unsigned short e1 = kw < 2 ? sy.h : (kw == 2 ? sy.m : (unsigned short)0);
        const unsigned short e2 = kw < 2 ? sq.h : (kw == 2 ? sq.m : (unsigned short)0);
        const unsigned short e3 = kw < 2 ? (unsigned short)0x3F80 : (unsigned short)0;
        // hi-half quad (k 4-7): kw0 -> H ; kw1 -> M ; kw2 -> L ; kw3 -> 0
        const unsigned short e4 = kw == 0 ? sx.h : (kw == 1 ? sx.m : (kw == 2 ? sx.l : (unsigned short)0));
        const unsigned short e5 = kw == 0 ? sy.h : (kw == 1 ? sy.m : (kw == 2 ? sy.l : (unsigned short)0));
        const unsigned short e6 = kw == 0 ? sq.h : (kw == 1 ? sq.m : (kw == 2 ? sq.l : (unsigned short)0));
        const unsigned short e7 = kw == 0 ? (unsigned short)0x3F80 : (unsigned short)0;
        bf16x8 A;
        A[0] = (short)e0; A[1] = (short)e1; A[2] = (short)e2; A[3] = (short)e3;
        A[4] = (short)e4; A[5] = (short)e5; A[6] = (short)e6; A[7] = (short)e7;
        af[tt] = A;
    }

    __syncthreads();

    // ---- main loop: 2 B-tiles x 4 A-tiles = 8 MFMA (2048 pairs) per iter ----
    const bf16x8* bptr = (const bf16x8*)&bfrag[0][0][0];
    const f32x4 zero = {0.f, 0.f, 0.f, 0.f};
    f32x4 nmin[4];
    #pragma unroll
    for (int tt = 0; tt < 4; ++tt) { nmin[tt][0]=INF; nmin[tt][1]=INF; nmin[tt][2]=INF; nmin[tt][3]=INF; }

    #pragma unroll 2
    for (int mt = 0; mt < 64; mt += 2) {
        const bf16x8 b0 = bptr[(mt    ) * 64 + l];
        const bf16x8 b1 = bptr[(mt + 1) * 64 + l];
        float cm0 = INF, cm1 = INF;
        #pragma unroll
        for (int tt = 0; tt < 4; ++tt) {
            const f32x4 c0 = __builtin_amdgcn_mfma_f32_16x16x32_bf16(af[tt], b0, zero, 0, 0, 0);
            const f32x4 c1 = __builtin_amdgcn_mfma_f32_16x16x32_bf16(af[tt], b1, zero, 0, 0, 0);
            #pragma unroll
            for (int r = 0; r < 4; ++r)
                nmin[tt][r] = fminf(fminf(nmin[tt][r], c0[r]), c1[r]);
            cm0 = fminf(fminf(fminf(c0[0], c0[1]), fminf(c0[2], c0[3])), cm0);
            cm1 = fminf(fminf(fminf(c1[0], c1[1]), fminf(c1[2], c1[3])), cm1);
        }
        // col-min partial for this rowgroup (int-ordered == float-ordered here)
        atomicMin(&smmin[kw * 1024 + mt * 16 + row],      __float_as_int(cm0));
        atomicMin(&smmin[kw * 1024 + mt * 16 + 16 + row], __float_as_int(cm1));
    }

    // ---- nmin: reduce across the 16 col-lanes, then global atomicMin ----
    #pragma unroll
    for (int tt = 0; tt < 4; ++tt) {
        #pragma unroll
        for (int r = 0; r < 4; ++r) {
            float v = nmin[tt][r];
            v = fminf(v, __shfl_xor(v, 1));
            v = fminf(v, __shfl_xor(v, 2));
            v = fminf(v, __shfl_xor(v, 4));
            v = fminf(v, __shfl_xor(v, 8));
            if (row == 0)   // lanes 0,16,32,48: output row = kw*4 + r
                atomicMin(&gn[b * 4096 + nc * 512 + w * 64 + tt * 16 + kw * 4 + r],
                          __float_as_int(v));
        }
    }

    // ---- mmin: fold 4 rowgroups, then global atomicMin ----
    __syncthreads();
    #pragma unroll
    for (int k = 0; k < 2; ++k) {
        const int i = t + k * 512;
        const int v = min(min(smmin[i], smmin[i + 1024]),
                          min(smmin[i + 2048], smmin[i + 3072]));
        atomicMin(&gm[b * 4096 + mq * 1024 + i], v);
    }
}

// 64 blocks x 256 thr: sqrt + partial sums over all 65536 min-slots.
__global__ __launch_bounds__(256) void chamfer_red1(
    const int* __restrict__ mins, float* __restrict__ part)
{
    __shared__ float wsum[4];
    const int t = threadIdx.x;
    const int4 v = ((const int4*)mins)[blockIdx.x * 256 + t];
    float s = sqrtf(fmaxf(__int_as_float(v.x), 0.f))
            + sqrtf(fmaxf(__int_as_float(v.y), 0.f))
            + sqrtf(fmaxf(__int_as_float(v.z), 0.f))
            + sqrtf(fmaxf(__int_as_float(v.w), 0.f));
    s += __shfl_down(s, 32);
    s += __shfl_down(s, 16);
    s += __shfl_down(s, 8);
    s += __shfl_down(s, 4);
    s += __shfl_down(s, 2);
    s += __shfl_down(s, 1);
    if ((t & 63) == 0) wsum[t >> 6] = s;
    __syncthreads();
    if (t == 0) part[blockIdx.x] = (wsum[0] + wsum[1]) + (wsum[2] + wsum[3]);
}

__global__ __launch_bounds__(64) void chamfer_red2(
    const float* __restrict__ part, float* __restrict__ out)
{
    float v = part[threadIdx.x];
    v += __shfl_down(v, 32);
    v += __shfl_down(v, 16);
    v += __shfl_down(v, 8);
    v += __shfl_down(v, 4);
    v += __shfl_down(v, 2);
    v += __shfl_down(v, 1);
    // mean(d_t_to_x) + mean(d_x_to_t): both halves divide by B*4096 = 32768
    if (threadIdx.x == 0) out[0] = v * (1.0f / 32768.0f);
}

extern "C" void kernel_launch(void* const* d_in, const int* in_sizes, int n_in,
                              void* d_out, int out_size, void* d_ws, size_t ws_size,
                              hipStream_t stream) {
    const float* x   = (const float*)d_in[0];
    const float* tgt = (const float*)d_in[1];
    int*   gn   = (int*)d_ws;            // [8][4096] row mins (d_x_to_t)
    int*   gm   = gn + 32768;            // [8][4096] col mins (d_t_to_x)
    float* part = (float*)(gn + 65536);  // 64 block partials
    float* out  = (float*)d_out;

    hipMemsetAsync(d_ws, 0x7F, 65536 * sizeof(int), stream);  // +3.39e38 pattern
    chamfer_gemm<<<dim3(256), dim3(512), 0, stream>>>(x, tgt, gn, gm);
    chamfer_red1<<<dim3(64),  dim3(256), 0, stream>>>(gn, part);
    chamfer_red2<<<dim3(1),   dim3(64),  0, stream>>>(part, out);
}

// Round 11
// 29.795 us; speedup vs baseline: 1.0238x; 1.0238x over previous
//
#include <hip/hip_runtime.h>
#include <math.h>

// Problem constants (B=8, N=M=4096, D=2).
// d2[n][m] = dot(A_n, B_m), A_n=[-2x,-2y,|x|^2,1], B_m=[tx,ty,1,|t|^2] (K=4),
// exact to ~1e-5 via 3-way bf16 splits over K=24 (pairs hh,hm,hl,mh,mm,lh)
// in ONE mfma_f32_16x16x32_bf16 (fragment layouts verified in R10, absmax 0.0).
#define NPTS 4096

typedef short bf16x8 __attribute__((ext_vector_type(8)));
typedef float f32x4  __attribute__((ext_vector_type(4)));
#define INF __builtin_huge_valf()

static __device__ __forceinline__ unsigned short rne16(float v, float* f) {
    unsigned u = __float_as_uint(v);
    unsigned r = (u + 0x7FFFu + ((u >> 16) & 1u)) & 0xFFFF0000u;
    *f = __uint_as_float(r);
    return (unsigned short)(r >> 16);
}
struct S3 { unsigned short h, m, l; };
static __device__ __forceinline__ S3 split3(float v) {
    S3 s; float hf, mf, lf;
    s.h = rne16(v, &hf);
    float r1 = v - hf;
    s.m = rne16(r1, &mf);
    float r2 = r1 - mf;
    s.l = rne16(r2, &lf);
    return s;
}
static __device__ __forceinline__ float min3f(float a, float b, float c) {
    float d;
    asm("v_min3_f32 %0, %1, %2, %3" : "=v"(d) : "v"(a), "v"(b), "v"(c));
    return d;
}

// 2048 blocks = 8 batches x 16 nq x 16 mq; 256 thr (4 waves).
// Block tile: 256 rows x 256 cols. Wave w owns rows w*64..w*64+63 (4 A-tiles),
// loops 16 B-tiles from LDS. Row-mins in regs -> LDS transpose -> unique
// global slot. Col-mins via kw-shfl-fold -> plain per-wave LDS -> unique slot.
// NO atomics anywhere.
__global__ __launch_bounds__(256, 4) void chamfer_gemm(
    const float* __restrict__ x, const float* __restrict__ tgt,
    float* __restrict__ gn_part, float* __restrict__ gm_part)
{
    __shared__ short bfrag[16][64][8];     // 16 KB B fragments (verified layout)
    __shared__ float colmin[4][256];       // 4 KB per-wave col mins
    __shared__ float rowpart[4][64][17];   // 17.4 KB row-min transpose (padded)

    const int bid = blockIdx.x;
    const int b   = bid >> 8;
    const int nq  = (bid >> 4) & 15;
    const int mq  = bid & 15;
    const int t   = threadIdx.x;
    const int l   = t & 63, w = t >> 6;
    const int kw  = l >> 4;

    // ---- B fragments: 1 point/thread (cols mq*256 + t) ----
    // B K-groups over kw: [Bh|Bm], [Bl|Bh], [Bm|Bh], [0|0]
    const float2* bp = (const float2*)(tgt + b * (NPTS * 2)) + mq * 256;
    {
        const float2 p = bp[t];
        const S3 sx = split3(p.x), sy = split3(p.y);
        const S3 sq = split3(fmaf(p.x, p.x, p.y * p.y));
        const unsigned H0 = (unsigned)sx.h | ((unsigned)sy.h << 16);
        const unsigned H1 = 0x3F80u | ((unsigned)sq.h << 16);
        const unsigned M0 = (unsigned)sx.m | ((unsigned)sy.m << 16);
        const unsigned M1 = ((unsigned)sq.m << 16);
        const unsigned L0 = (unsigned)sx.l | ((unsigned)sy.l << 16);
        const unsigned L1 = ((unsigned)sq.l << 16);
        const int tile = t >> 4, c = t & 15;
        *(uint4*)&bfrag[tile][ 0 + c][0] = make_uint4(H0, H1, M0, M1);
        *(uint4*)&bfrag[tile][16 + c][0] = make_uint4(L0, L1, H0, H1);
        *(uint4*)&bfrag[tile][32 + c][0] = make_uint4(M0, M1, H0, H1);
        *(uint4*)&bfrag[tile][48 + c][0] = make_uint4(0, 0, 0, 0);
    }

    // ---- A fragments: 4 tiles (rows nq*256 + w*64 + tt*16 + row) ----
    // A K-groups over kw: [Ah|Ah], [Ah|Am], [Am|Al], [0|0]
    const float2* ap = (const float2*)(x + b * (NPTS * 2)) + nq * 256 + w * 64;
    bf16x8 af[4];
    #pragma unroll
    for (int tt = 0; tt < 4; ++tt) {
        const float2 p = ap[tt * 16 + (l & 15)];
        const S3 sx = split3(-2.f * p.x), sy = split3(-2.f * p.y);
        const S3 sq = split3(fmaf(p.x, p.x, p.y * p.y));
        const unsigned short e0 = kw < 2 ? sx.h : (kw == 2 ? sx.m : (unsigned short)0);
        const unsigned short e1 = kw < 2 ? sy.h : (kw == 2 ? sy.m : (unsigned short)0);
        const unsigned short e2 = kw < 2 ? sq.h : (kw == 2 ? sq.m : (unsigned short)0);
        const unsigned short e3 = kw < 2 ? (unsigned short)0x3F80 : (unsigned short)0;
        const unsigned short e4 = kw == 0 ? sx.h : (kw == 1 ? sx.m : (kw == 2 ? sx.l : (unsigned short)0));
        const unsigned short e5 = kw == 0 ? sy.h : (kw == 1 ? sy.m : (kw == 2 ? sy.l : (unsigned short)0));
        const unsigned short e6 = kw == 0 ? sq.h : (kw == 1 ? sq.m : (kw == 2 ? sq.l : (unsigned short)0));
        const unsigned short e7 = kw == 0 ? (unsigned short)0x3F80 : (unsigned short)0;
        bf16x8 A;
        A[0] = (short)e0; A[1] = (short)e1; A[2] = (short)e2; A[3] = (short)e3;
        A[4] = (short)e4; A[5] = (short)e5; A[6] = (short)e6; A[7] = (short)e7;
        af[tt] = A;
    }

    __syncthreads();

    // ---- main loop: 16 B-tiles x 4 A-tiles; fold mins, no atomics ----
    const bf16x8* bptr = (const bf16x8*)&bfrag[0][0][0];
    const f32x4 zero = {0.f, 0.f, 0.f, 0.f};
    f32x4 rmin[4];
    #pragma unroll
    for (int tt = 0; tt < 4; ++tt) rmin[tt] = (f32x4){INF, INF, INF, INF};

    #pragma unroll 4
    for (int mt = 0; mt < 16; ++mt) {
        const bf16x8 bb = bptr[mt * 64 + l];   // conflict-free b128
        float cmin = INF;
        #pragma unroll
        for (int tt = 0; tt < 4; ++tt) {
            const f32x4 c = __builtin_amdgcn_mfma_f32_16x16x32_bf16(af[tt], bb, zero, 0, 0, 0);
            rmin[tt][0] = fminf(rmin[tt][0], c[0]);
            rmin[tt][1] = fminf(rmin[tt][1], c[1]);
            rmin[tt][2] = fminf(rmin[tt][2], c[2]);
            rmin[tt][3] = fminf(rmin[tt][3], c[3]);
            cmin = min3f(cmin, fminf(c[0], c[1]), fminf(c[2], c[3]));
        }
        // fold across the 4 kw row-groups -> full 64-row col-min
        cmin = fminf(cmin, __shfl_xor(cmin, 16));
        cmin = fminf(cmin, __shfl_xor(cmin, 32));
        if (l < 16) colmin[w][mt * 16 + l] = cmin;  // plain write, no conflict
    }

    // ---- row-min transpose: regs -> padded per-wave LDS (conflict-free) ----
    #pragma unroll
    for (int tt = 0; tt < 4; ++tt) {
        #pragma unroll
        for (int r = 0; r < 4; ++r)
            rowpart[w][tt * 16 + kw * 4 + r][l & 15] = rmin[tt][r];
    }
    __syncthreads();

    // ---- refold + unique-slot global stores (no atomics) ----
    {
        const float* rp = &rowpart[w][l][0];
        float v = rp[0];
        #pragma unroll
        for (int c = 1; c < 16; ++c) v = fminf(v, rp[c]);
        gn_part[(b * 16 + mq) * 4096 + nq * 256 + t] = v;

        float u = fminf(fminf(colmin[0][t], colmin[1][t]),
                        fminf(colmin[2][t], colmin[3][t]));
        gm_part[(b * 16 + nq) * 4096 + mq * 256 + t] = u;
    }
}

// 128 blocks x 256 thr: fold 16 partials per row/col, sqrt, block-sum.
// bid<64: gn side (rows); bid>=64: gm side (cols). 512 slots per block.
__global__ __launch_bounds__(256) void chamfer_red1(
    const float* __restrict__ parts, float* __restrict__ blocksum)
{
    __shared__ float wsum[4];
    const int bid = blockIdx.x;
    const int t   = threadIdx.x;
    const float* src = parts + (size_t)(bid >> 6) * 524288;
    const int base = (bid & 63) * 512;
    float s = 0.f;
    #pragma unroll
    for (int k = 0; k < 2; ++k) {
        const int R = base + k * 256 + t;      // [0, 32768)
        const int b = R >> 12, n = R & 4095;
        const float* p = src + b * 65536 + n;
        float v = p[0];
        #pragma unroll
        for (int f = 1; f < 16; ++f) v = fminf(v, p[f * 4096]);
        s += sqrtf(fmaxf(v, 0.f));
    }
    s += __shfl_down(s, 32);
    s += __shfl_down(s, 16);
    s += __shfl_down(s, 8);
    s += __shfl_down(s, 4);
    s += __shfl_down(s, 2);
    s += __shfl_down(s, 1);
    if ((t & 63) == 0) wsum[t >> 6] = s;
    __syncthreads();
    if (t == 0) blocksum[bid] = (wsum[0] + wsum[1]) + (wsum[2] + wsum[3]);
}

__global__ __launch_bounds__(64) void chamfer_red2(
    const float* __restrict__ blocksum, float* __restrict__ out)
{
    float v = blocksum[threadIdx.x] + blocksum[threadIdx.x + 64];
    v += __shfl_down(v, 32);
    v += __shfl_down(v, 16);
    v += __shfl_down(v, 8);
    v += __shfl_down(v, 4);
    v += __shfl_down(v, 2);
    v += __shfl_down(v, 1);
    // mean(d_t_to_x) + mean(d_x_to_t): both halves divide by B*4096 = 32768
    if (threadIdx.x == 0) out[0] = v * (1.0f / 32768.0f);
}

extern "C" void kernel_launch(void* const* d_in, const int* in_sizes, int n_in,
                              void* d_out, int out_size, void* d_ws, size_t ws_size,
                              hipStream_t stream) {
    const float* x   = (const float*)d_in[0];
    const float* tgt = (const float*)d_in[1];
    float* gn_part   = (float*)d_ws;            // [8][16][4096] row-min partials
    float* gm_part   = gn_part + 524288;        // [8][16][4096] col-min partials
    float* blocksum  = gn_part + 1048576;       // 128 floats
    float* out       = (float*)d_out;

    chamfer_gemm<<<dim3(2048), dim3(256), 0, stream>>>(x, tgt, gn_part, gm_part);
    chamfer_red1<<<dim3(128),  dim3(256), 0, stream>>>(gn_part, blocksum);
    chamfer_red2<<<dim3(1),    dim3(64),  0, stream>>>(blocksum, out);
}